// Round 2
// baseline (418.700 us; speedup 1.0000x reference)
//
#include <hip/hip_runtime.h>

// GraphSageConvOD: 2-iteration OD flow + SIR propagation + 12x64 dense + ReLU.
// B=8, T=2, N=2048. OD_all is 256 MB fp32; memory-bound.
//
// R2 structure (L3-reuse ordering + higher colacc occupancy):
//   rowsum<t=0> : row sums of OD[:,0]            (134 MB, HBM-cold)
//   prep0       : scale0, w0, pm0/stay0
//   colacc0     : acc0[b,j,f] = sum_i OD0[b,i,j]*w0[b,i,f]  (re-read of OD0 -> L3 hit)
//   rowsum<t=1> : row sums of OD[:,1]            (134 MB, HBM-cold)
//   prep1       : pop1/SIR1 from pm0+acc0; w1, pm1/stay1
//   colacc1     : acc1 = OD1^T @ w1              (re-read of OD1 -> L3 hit)
//   final       : SIR2(12f) @ kernel(12x64) + bias, relu; concat pop2
//
// colacc: 256-col x 128-row tiles -> 1024 blocks (4/CU), software-pipelined
// loads (2 in flight/wave) to cover HBM/L3 latency.

#define DELTA 1e-7f
constexpr int B = 8, N = 2048, T = 2;
constexpr int NB = B * N; // 16384

// ws layout (float offsets)
constexpr int RS_OFF   = 0;                 // row sums [t][b][i]  : 2*NB
constexpr int W0_OFF   = RS_OFF  + 2 * NB;  // w0  [b][i][4]
constexpr int ST0_OFF  = W0_OFF  + NB * 4;  // {pm0, stay0[3]}
constexpr int W1_OFF   = ST0_OFF + NB * 4;  // w1  [b][i][8] (7 used)
constexpr int ST1_OFF  = W1_OFF  + NB * 8;  // {pm1, stay1[6], pad}
constexpr int ACC0_OFF = ST1_OFF + NB * 8;  // acc0 [b][j][4]  (zeroed)
constexpr int ACC1_OFF = ACC0_OFF + NB * 4; // acc1 [b][j][7]  (zeroed)
constexpr int WS_END   = ACC1_OFF + NB * 7;

// ---- rowsum for one t: one wave per row; 2048 floats = 8 float4 per lane ----
__global__ void __launch_bounds__(256) rowsum_kernel(const float* __restrict__ OD_all,
                                                     const int t,
                                                     float* __restrict__ rs) {
  const int quad = threadIdx.x >> 6, lane = threadIdx.x & 63;
  const int r = blockIdx.x * 4 + quad;  // flat over [b][i], 0..16383
  const int b = r >> 11, i = r & (N - 1);
  const float4* p = (const float4*)(OD_all + ((size_t)(b * T + t) * N + i) * N);
  float s = 0.f;
#pragma unroll
  for (int k = 0; k < 8; ++k) {
    float4 v = p[lane + 64 * k];
    s += (v.x + v.y) + (v.z + v.w);
  }
#pragma unroll
  for (int off = 32; off; off >>= 1) s += __shfl_down(s, off, 64);
  if (lane == 0) rs[t * NB + r] = s;
}

// ---- B0: per-(b,i) iteration-0 prep ----
__global__ void __launch_bounds__(256) prep0_kernel(const float* __restrict__ feat,
                                                    const float* __restrict__ rs,
                                                    float* __restrict__ w0,
                                                    float* __restrict__ st0) {
  const int g = blockIdx.x * 256 + threadIdx.x;  // b*N+i
  const float4 f = ((const float4*)feat)[g];
  const float pop = f.x;
  const float rs0 = rs[g];
  const float ratio = pop / (DELTA + rs0);
  const float scale = ratio < 1.f ? ratio : 1.f;
  const float inv = 1.f / (DELTA + pop);
  const float sn0 = f.y * inv, sn1 = f.z * inv, sn2 = f.w * inv;
  const float odout = scale * rs0;
  ((float4*)w0)[g]  = make_float4(scale, scale * sn0, scale * sn1, scale * sn2);
  ((float4*)st0)[g] = make_float4(pop - odout, f.y - odout * sn0,
                                  f.z - odout * sn1, f.w - odout * sn2);
}

// ---- colacc: acc[b,j,f] += sum_i OD[b,t,i,j] * w[b,i,f]
// 256-col x 128-row tile per block; wave 'quad' walks rows quad+4k, k<32.
// Software-pipelined: next row's float4 issued before current row's FMAs.
template <int NF, int WSTRIDE>
__global__ void __launch_bounds__(256) colacc_kernel(const float* __restrict__ OD_all,
                                                     const int t,
                                                     const float* __restrict__ w,
                                                     float* __restrict__ acc) {
  constexpr int TI = 128;  // rows per block
  constexpr int KI = TI / 4;
  const int tid = threadIdx.x;
  const int quad = tid >> 6, lane = tid & 63;
  const int jbase = blockIdx.x * 256;
  const int ibase = blockIdx.y * TI;
  const int b = blockIdx.z;

  __shared__ float wlds[TI * WSTRIDE];
  {
    const float4* src = (const float4*)(w + (size_t)(b * N + ibase) * WSTRIDE);
    float4* dst = (float4*)wlds;
#pragma unroll
    for (int x = tid; x < TI * WSTRIDE / 4; x += 256) dst[x] = src[x];
  }
  __syncthreads();

  float accr[4][NF];
#pragma unroll
  for (int c = 0; c < 4; ++c)
#pragma unroll
    for (int f = 0; f < NF; ++f) accr[c][f] = 0.f;

  const float* odbase =
      OD_all + ((size_t)(b * T + t) * N + ibase) * N + jbase + lane * 4;
  float4 cur = *(const float4*)(odbase + (size_t)quad * N);
  for (int k = 0; k < KI; ++k) {
    const int r = quad + 4 * k;
    float4 nxt;
    if (k + 1 < KI) nxt = *(const float4*)(odbase + (size_t)(r + 4) * N);
#pragma unroll
    for (int f = 0; f < NF; ++f) {
      const float wv = wlds[r * WSTRIDE + f];  // wave-uniform -> LDS broadcast
      accr[0][f] += cur.x * wv;
      accr[1][f] += cur.y * wv;
      accr[2][f] += cur.z * wv;
      accr[3][f] += cur.w * wv;
    }
    cur = nxt;
  }
  __syncthreads();

  __shared__ float red[4][256 * NF];
#pragma unroll
  for (int c = 0; c < 4; ++c)
#pragma unroll
    for (int f = 0; f < NF; ++f)
      red[quad][(lane * 4 + c) * NF + f] = accr[c][f];
  __syncthreads();

  for (int x = tid; x < 256 * NF; x += 256) {
    const float s = red[0][x] + red[1][x] + red[2][x] + red[3][x];
    const int colx = x / NF, f = x - colx * NF;
    atomicAdd(&acc[(size_t)(b * N + jbase + colx) * NF + f], s);
  }
}

// ---- B1: per-(b,j) iteration-1 prep ----
__global__ void __launch_bounds__(256) prep1_kernel(const float* __restrict__ st0,
                                                    const float* __restrict__ acc0,
                                                    const float* __restrict__ rs,
                                                    float* __restrict__ w1,
                                                    float* __restrict__ st1) {
  const int g = blockIdx.x * 256 + threadIdx.x;
  const float4 s0 = ((const float4*)st0)[g];
  const float4 a0 = ((const float4*)acc0)[g];
  const float rs1 = rs[NB + g];
  const float pop = s0.x + a0.x;  // pm0 + OD_in0
  const float S[6] = {s0.y, s0.z, s0.w, a0.y, a0.z, a0.w};  // [stay0, in0]
  const float ratio = pop / (DELTA + rs1);
  const float scale = ratio < 1.f ? ratio : 1.f;
  const float inv = 1.f / (DELTA + pop);
  const float odout = scale * rs1;
  float wv[8], sv[8];
  wv[0] = scale;
  sv[0] = pop - odout;
#pragma unroll
  for (int f = 0; f < 6; ++f) {
    const float sn = S[f] * inv;
    wv[1 + f] = scale * sn;
    sv[1 + f] = S[f] - odout * sn;
  }
  wv[7] = 0.f;
  sv[7] = 0.f;
  float4* w4 = (float4*)(w1 + (size_t)g * 8);
  w4[0] = make_float4(wv[0], wv[1], wv[2], wv[3]);
  w4[1] = make_float4(wv[4], wv[5], wv[6], wv[7]);
  float4* s4 = (float4*)(st1 + (size_t)g * 8);
  s4[0] = make_float4(sv[0], sv[1], sv[2], sv[3]);
  s4[1] = make_float4(sv[4], sv[5], sv[6], sv[7]);
}

// ---- final: output = concat(pop2, relu(SIR2 @ K + bias)) ----
__global__ void __launch_bounds__(256) final_kernel(const float* __restrict__ st1,
                                                    const float* __restrict__ acc1,
                                                    const float* __restrict__ kern,
                                                    const float* __restrict__ bias,
                                                    float* __restrict__ out) {
  __shared__ float klds[12 * 64];
  const int tid = threadIdx.x;
  if (tid < 192) ((float4*)klds)[tid] = ((const float4*)kern)[tid];
  __syncthreads();
  const int p = blockIdx.x * 4 + (tid >> 6);  // b*N+n
  const int c = tid & 63;
  const float4* s4 = (const float4*)(st1 + (size_t)p * 8);
  const float4 l0 = s4[0], l1 = s4[1];
  const float* a = acc1 + (size_t)p * 7;
  const float S[12] = {l0.y, l0.z, l0.w, l1.x, l1.y, l1.z,
                       a[1], a[2], a[3], a[4], a[5], a[6]};
  float sum = bias[c];
#pragma unroll
  for (int f = 0; f < 12; ++f) sum += S[f] * klds[f * 64 + c];
  float* o = out + (size_t)p * 65;
  o[1 + c] = sum > 0.f ? sum : 0.f;
  if (c == 0) o[0] = l0.x + a[0];  // pop2 = pm1 + OD_in1
}

extern "C" void kernel_launch(void* const* d_in, const int* in_sizes, int n_in,
                              void* d_out, int out_size, void* d_ws, size_t ws_size,
                              hipStream_t stream) {
  const float* feat = (const float*)d_in[0];  // (8,2048,4)
  const float* OD   = (const float*)d_in[1];  // (8,2,2048,2048)
  const float* kern = (const float*)d_in[2];  // (12,64)
  const float* bias = (const float*)d_in[3];  // (64,)
  float* out = (float*)d_out;                 // (8,2048,65)
  float* ws = (float*)d_ws;

  float* rs   = ws + RS_OFF;
  float* w0   = ws + W0_OFF;
  float* st0  = ws + ST0_OFF;
  float* w1   = ws + W1_OFF;
  float* st1  = ws + ST1_OFF;
  float* acc0 = ws + ACC0_OFF;
  float* acc1 = ws + ACC1_OFF;

  // zero the atomic accumulators (acc0+acc1 are contiguous)
  hipMemsetAsync(acc0, 0, (size_t)(WS_END - ACC0_OFF) * sizeof(float), stream);

  dim3 gc(N / 256, N / 128, B);
  // t = 0 epoch (OD0 stays L3-resident between rowsum and colacc)
  rowsum_kernel<<<NB / 4, 256, 0, stream>>>(OD, 0, rs);
  prep0_kernel<<<NB / 256, 256, 0, stream>>>(feat, rs, w0, st0);
  colacc_kernel<4, 4><<<gc, 256, 0, stream>>>(OD, 0, w0, acc0);
  // t = 1 epoch
  rowsum_kernel<<<NB / 4, 256, 0, stream>>>(OD, 1, rs);
  prep1_kernel<<<NB / 256, 256, 0, stream>>>(st0, acc0, rs, w1, st1);
  colacc_kernel<7, 8><<<gc, 256, 0, stream>>>(OD, 1, w1, acc1);
  final_kernel<<<NB / 4, 256, 0, stream>>>(st1, acc1, kern, bias, out);
}

// Round 3
// 413.084 us; speedup vs baseline: 1.0136x; 1.0136x over previous
//
#include <hip/hip_runtime.h>

// GraphSageConvOD: 2-iteration OD flow + SIR propagation + 12x64 dense + ReLU.
// B=8, T=2, N=2048. OD_all is 256 MB fp32; memory-bound.
//
// R3 structure (5 dispatches, overlapped pipeline):
//   rs0_prep0   : row sums of OD[:,0] fused with prep0 -> w0, st0 (no rs0 store)
//   colacc0_rs1 : block-partitioned single kernel:
//                   blocks <1024 : acc0 = OD0^T @ w0   (OD0 -> L3 hit after rs0 pass)
//                   blocks >=1024: rs1 row sums of OD[:,1]  (HBM-cold, overlaps)
//   prep1       : pop1/SIR1 from pm0+acc0; w1, st1
//   colacc1     : acc1 = OD1^T @ w1     (OD1 -> L3 hit after rs1 pass)
//   final       : SIR2(12f) @ kernel(12x64) + bias, relu; concat pop2
//
// Kernel-time model: 22 + max(13,20) + 2 + 15 + 3 ~= 65-75 us.
// HBM floor for this dependency chain: 268 MB cold reads ~= 40 us.

#define DELTA 1e-7f
constexpr int B = 8, N = 2048;
constexpr int NB = B * N;  // 16384

// ws layout (float offsets)
constexpr int RS1_OFF  = 0;                 // rs1 [b][i]       : NB
constexpr int W0_OFF   = RS1_OFF + NB;      // w0  [b][i][4]
constexpr int ST0_OFF  = W0_OFF  + NB * 4;  // {pm0, stay0[3]}
constexpr int W1_OFF   = ST0_OFF + NB * 4;  // w1  [b][i][8] (7 used)
constexpr int ST1_OFF  = W1_OFF  + NB * 8;  // {pm1, stay1[6], pad}
constexpr int ACC0_OFF = ST1_OFF + NB * 8;  // acc0 [b][j][4]  (zeroed)
constexpr int ACC1_OFF = ACC0_OFF + NB * 4; // acc1 [b][j][7]  (zeroed)
constexpr int WS_END   = ACC1_OFF + NB * 7;

// ---- rowsum(t=0) fused with prep0: one wave per row ----
__global__ void __launch_bounds__(256) rs0_prep0_kernel(const float* __restrict__ OD,
                                                        const float* __restrict__ feat,
                                                        float* __restrict__ w0,
                                                        float* __restrict__ st0) {
  const int quad = threadIdx.x >> 6, lane = threadIdx.x & 63;
  const int r = blockIdx.x * 4 + quad;  // flat over [b][i]
  const int b = r >> 11, i = r & (N - 1);
  const float4* p = (const float4*)(OD + ((size_t)(b * 2) * N + i) * N);
  float s = 0.f;
#pragma unroll
  for (int k = 0; k < 8; ++k) {
    float4 v = p[lane + 64 * k];
    s += (v.x + v.y) + (v.z + v.w);
  }
#pragma unroll
  for (int off = 32; off; off >>= 1) s += __shfl_down(s, off, 64);
  if (lane == 0) {
    const float4 f = ((const float4*)feat)[r];
    const float pop = f.x;
    const float ratio = pop / (DELTA + s);
    const float scale = ratio < 1.f ? ratio : 1.f;
    const float inv = 1.f / (DELTA + pop);
    const float sn0 = f.y * inv, sn1 = f.z * inv, sn2 = f.w * inv;
    const float odout = scale * s;
    ((float4*)w0)[r]  = make_float4(scale, scale * sn0, scale * sn1, scale * sn2);
    ((float4*)st0)[r] = make_float4(pop - odout, f.y - odout * sn0,
                                    f.z - odout * sn1, f.w - odout * sn2);
  }
}

// ---- fused: colacc over OD0 (blocks 0..1023) || rowsum over OD1 (blocks 1024..2047) ----
__global__ void __launch_bounds__(256) colacc0_rs1_kernel(const float* __restrict__ OD,
                                                          const float* __restrict__ w0,
                                                          float* __restrict__ acc0,
                                                          float* __restrict__ rs1) {
  __shared__ float wlds[128 * 4];
  __shared__ float red[4][256 * 4];
  const int tid = threadIdx.x, quad = tid >> 6, lane = tid & 63;
  const int bid = blockIdx.x;
  if (bid < 1024) {
    // ---- colacc0: 256-col x 128-row tile ----
    const int jt = bid & 7, it = (bid >> 3) & 15, b = bid >> 7;
    const int jbase = jt * 256, ibase = it * 128;
    {
      const float4* src = (const float4*)(w0 + (size_t)(b * N + ibase) * 4);
      for (int x = tid; x < 128; x += 256) ((float4*)wlds)[x] = src[x];
    }
    __syncthreads();
    float accr[4][4] = {};
    const float* odbase = OD + ((size_t)(b * 2) * N + ibase) * N + jbase + lane * 4;
    float4 cur = *(const float4*)(odbase + (size_t)quad * N);
    for (int k = 0; k < 32; ++k) {
      const int r = quad + 4 * k;
      float4 nxt;
      if (k + 1 < 32) nxt = *(const float4*)(odbase + (size_t)(r + 4) * N);
#pragma unroll
      for (int f = 0; f < 4; ++f) {
        const float wv = wlds[r * 4 + f];  // wave-uniform -> LDS broadcast
        accr[0][f] += cur.x * wv;
        accr[1][f] += cur.y * wv;
        accr[2][f] += cur.z * wv;
        accr[3][f] += cur.w * wv;
      }
      cur = nxt;
    }
    __syncthreads();
#pragma unroll
    for (int c = 0; c < 4; ++c)
#pragma unroll
      for (int f = 0; f < 4; ++f)
        red[quad][(lane * 4 + c) * 4 + f] = accr[c][f];
    __syncthreads();
    for (int x = tid; x < 1024; x += 256) {
      const float sred = red[0][x] + red[1][x] + red[2][x] + red[3][x];
      const int colx = x >> 2, f = x & 3;
      atomicAdd(&acc0[(size_t)(b * N + jbase + colx) * 4 + f], sred);
    }
  } else {
    // ---- rowsum(t=1): 16 rows per block, 4 per wave ----
    const int rb = bid - 1024;
#pragma unroll
    for (int m = 0; m < 4; ++m) {
      const int r = rb * 16 + quad * 4 + m;
      const int b = r >> 11, i = r & (N - 1);
      const float4* p = (const float4*)(OD + ((size_t)(b * 2 + 1) * N + i) * N);
      float s = 0.f;
#pragma unroll
      for (int k = 0; k < 8; ++k) {
        float4 v = p[lane + 64 * k];
        s += (v.x + v.y) + (v.z + v.w);
      }
#pragma unroll
      for (int off = 32; off; off >>= 1) s += __shfl_down(s, off, 64);
      if (lane == 0) rs1[r] = s;
    }
  }
}

// ---- prep1: per-(b,j) iteration-1 prep ----
__global__ void __launch_bounds__(256) prep1_kernel(const float* __restrict__ st0,
                                                    const float* __restrict__ acc0,
                                                    const float* __restrict__ rs1,
                                                    float* __restrict__ w1,
                                                    float* __restrict__ st1) {
  const int g = blockIdx.x * 256 + threadIdx.x;
  const float4 s0 = ((const float4*)st0)[g];
  const float4 a0 = ((const float4*)acc0)[g];
  const float rsv = rs1[g];
  const float pop = s0.x + a0.x;  // pm0 + OD_in0
  const float S[6] = {s0.y, s0.z, s0.w, a0.y, a0.z, a0.w};  // [stay0, in0]
  const float ratio = pop / (DELTA + rsv);
  const float scale = ratio < 1.f ? ratio : 1.f;
  const float inv = 1.f / (DELTA + pop);
  const float odout = scale * rsv;
  float wv[8], sv[8];
  wv[0] = scale;
  sv[0] = pop - odout;
#pragma unroll
  for (int f = 0; f < 6; ++f) {
    const float sn = S[f] * inv;
    wv[1 + f] = scale * sn;
    sv[1 + f] = S[f] - odout * sn;
  }
  wv[7] = 0.f;
  sv[7] = 0.f;
  float4* w4 = (float4*)(w1 + (size_t)g * 8);
  w4[0] = make_float4(wv[0], wv[1], wv[2], wv[3]);
  w4[1] = make_float4(wv[4], wv[5], wv[6], wv[7]);
  float4* s4 = (float4*)(st1 + (size_t)g * 8);
  s4[0] = make_float4(sv[0], sv[1], sv[2], sv[3]);
  s4[1] = make_float4(sv[4], sv[5], sv[6], sv[7]);
}

// ---- colacc1: acc1[b,j,f] += sum_i OD1[b,i,j] * w1[b,i,f], NF=7 ----
__global__ void __launch_bounds__(256) colacc1_kernel(const float* __restrict__ OD,
                                                      const float* __restrict__ w1,
                                                      float* __restrict__ acc1) {
  constexpr int NF = 7, WS = 8;
  const int tid = threadIdx.x, quad = tid >> 6, lane = tid & 63;
  const int jbase = blockIdx.x * 256;
  const int ibase = blockIdx.y * 128;
  const int b = blockIdx.z;

  __shared__ float wlds[128 * WS];
  {
    const float4* src = (const float4*)(w1 + (size_t)(b * N + ibase) * WS);
    for (int x = tid; x < 256; x += 256) ((float4*)wlds)[x] = src[x];
  }
  __syncthreads();

  float accr[4][NF] = {};
  const float* odbase = OD + ((size_t)(b * 2 + 1) * N + ibase) * N + jbase + lane * 4;
  float4 cur = *(const float4*)(odbase + (size_t)quad * N);
  for (int k = 0; k < 32; ++k) {
    const int r = quad + 4 * k;
    float4 nxt;
    if (k + 1 < 32) nxt = *(const float4*)(odbase + (size_t)(r + 4) * N);
#pragma unroll
    for (int f = 0; f < NF; ++f) {
      const float wv = wlds[r * WS + f];
      accr[0][f] += cur.x * wv;
      accr[1][f] += cur.y * wv;
      accr[2][f] += cur.z * wv;
      accr[3][f] += cur.w * wv;
    }
    cur = nxt;
  }
  __syncthreads();

  __shared__ float red[4][256 * NF];
#pragma unroll
  for (int c = 0; c < 4; ++c)
#pragma unroll
    for (int f = 0; f < NF; ++f)
      red[quad][(lane * 4 + c) * NF + f] = accr[c][f];
  __syncthreads();

  for (int x = tid; x < 256 * NF; x += 256) {
    const float s = red[0][x] + red[1][x] + red[2][x] + red[3][x];
    const int colx = x / NF, f = x - colx * NF;
    atomicAdd(&acc1[(size_t)(b * N + jbase + colx) * NF + f], s);
  }
}

// ---- final: output = concat(pop2, relu(SIR2 @ K + bias)) ----
__global__ void __launch_bounds__(256) final_kernel(const float* __restrict__ st1,
                                                    const float* __restrict__ acc1,
                                                    const float* __restrict__ kern,
                                                    const float* __restrict__ bias,
                                                    float* __restrict__ out) {
  __shared__ float klds[12 * 64];
  const int tid = threadIdx.x;
  if (tid < 192) ((float4*)klds)[tid] = ((const float4*)kern)[tid];
  __syncthreads();
  const int p = blockIdx.x * 4 + (tid >> 6);  // b*N+n
  const int c = tid & 63;
  const float4* s4 = (const float4*)(st1 + (size_t)p * 8);
  const float4 l0 = s4[0], l1 = s4[1];
  const float* a = acc1 + (size_t)p * 7;
  const float S[12] = {l0.y, l0.z, l0.w, l1.x, l1.y, l1.z,
                       a[1], a[2], a[3], a[4], a[5], a[6]};
  float sum = bias[c];
#pragma unroll
  for (int f = 0; f < 12; ++f) sum += S[f] * klds[f * 64 + c];
  float* o = out + (size_t)p * 65;
  o[1 + c] = sum > 0.f ? sum : 0.f;
  if (c == 0) o[0] = l0.x + a[0];  // pop2 = pm1 + OD_in1
}

extern "C" void kernel_launch(void* const* d_in, const int* in_sizes, int n_in,
                              void* d_out, int out_size, void* d_ws, size_t ws_size,
                              hipStream_t stream) {
  const float* feat = (const float*)d_in[0];  // (8,2048,4)
  const float* OD   = (const float*)d_in[1];  // (8,2,2048,2048)
  const float* kern = (const float*)d_in[2];  // (12,64)
  const float* bias = (const float*)d_in[3];  // (64,)
  float* out = (float*)d_out;                 // (8,2048,65)
  float* ws = (float*)d_ws;

  float* rs1  = ws + RS1_OFF;
  float* w0   = ws + W0_OFF;
  float* st0  = ws + ST0_OFF;
  float* w1   = ws + W1_OFF;
  float* st1  = ws + ST1_OFF;
  float* acc0 = ws + ACC0_OFF;
  float* acc1 = ws + ACC1_OFF;

  // zero the atomic accumulators (acc0+acc1 contiguous)
  hipMemsetAsync(acc0, 0, (size_t)(WS_END - ACC0_OFF) * sizeof(float), stream);

  rs0_prep0_kernel<<<NB / 4, 256, 0, stream>>>(OD, feat, w0, st0);
  colacc0_rs1_kernel<<<2048, 256, 0, stream>>>(OD, w0, acc0, rs1);
  prep1_kernel<<<NB / 256, 256, 0, stream>>>(st0, acc0, rs1, w1, st1);
  colacc1_kernel<<<dim3(N / 256, N / 128, B), 256, 0, stream>>>(OD, w1, acc1);
  final_kernel<<<NB / 4, 256, 0, stream>>>(st1, acc1, kern, bias, out);
}

// Round 4
// 401.704 us; speedup vs baseline: 1.0423x; 1.0283x over previous
//
#include <hip/hip_runtime.h>

// GraphSageConvOD: 2-iteration OD flow + SIR propagation + 12x64 dense + ReLU.
// B=8, T=2, N=2048. OD_all is 256 MB fp32; memory-bound.
//
// R4: single-read structure. Each fused kernel reads its OD slice EXACTLY ONCE:
// a 512-thread block owns 64 rows of one batch; per group of 8 rows it holds
// the row data in registers (1 float4/lane/row, wave = 256-col slice),
// computes rowsums via shuffle + LDS cross-wave exchange, derives
// scale/w/st in-kernel, then FMAs the same registers into per-lane column
// accumulators. Per-block column partials -> scratch (no atomics, no memset).
//
//   fused0  : OD0 once -> part0[b][rb][j][4], st0[b][i][4]
//   prep1   : st0 + sum(part0) -> pre1[b][i][8] = {pop1, inv1, SIR1[0..5]}
//   fused1  : OD1 once -> part1[b][rb][j][8], st1[b][i][8]
//   reduce1 : sum(part1) -> acc1[b][j][8]
//   final   : concat(pop2, relu(SIR2 @ K + bias))
//
// Traffic ~= 256 MB OD + ~64 MB partials/etc ~= 52 us kernel-side floor.

#define DELTA 1e-7f
constexpr int B = 8, N = 2048;
constexpr int NB = B * N;     // 16384
constexpr int RPB = 64;       // rows per block (fused kernels)
constexpr int NRB = N / RPB;  // 32 row-blocks per batch

// ws float offsets
constexpr int ST0_OFF  = 0;                      // [b][i][4] {pm0, stay0[3]}
constexpr int PRE_OFF  = ST0_OFF + NB * 4;       // [b][i][8] {pop1, inv1, SIR1[0..5]}
constexpr int ST1_OFF  = PRE_OFF + NB * 8;       // [b][i][8] {pm1, stay1[0..5], 0}
constexpr int P0_OFF   = ST1_OFF + NB * 8;       // part0 [b][rb][j][4]
constexpr int P1_OFF   = P0_OFF + B * NRB * N * 4;  // part1 [b][rb][j][8]
constexpr int ACC1_OFF = P1_OFF + B * NRB * N * 8;  // [b][j][8]

__device__ __forceinline__ void fma4(float4& a, float s, const float4& w) {
  a.x = fmaf(s, w.x, a.x);
  a.y = fmaf(s, w.y, a.y);
  a.z = fmaf(s, w.z, a.z);
  a.w = fmaf(s, w.w, a.w);
}

// ---- fused0: t=0 rowsum + scale + column partials, OD0 read once ----
__global__ void __launch_bounds__(512) fused0_kernel(const float* __restrict__ OD,
                                                     const float* __restrict__ feat,
                                                     float* __restrict__ part0,
                                                     float* __restrict__ st0) {
  const int tid = threadIdx.x, w = tid >> 6, l = tid & 63;
  const int b = blockIdx.x >> 5, rb = blockIdx.x & 31, i0 = rb * RPB;
  __shared__ float4 ldsfeat[RPB];
  __shared__ float wpart[64];
  __shared__ float4 wv[8];
  if (tid < RPB) ldsfeat[tid] = ((const float4*)feat)[b * N + i0 + tid];
  __syncthreads();

  const float* odbase = OD + ((size_t)(b * 2) * N + i0) * N + w * 256 + l * 4;
  float4 acc[4] = {};
  float4 cur[8], nxt[8];
#pragma unroll
  for (int m = 0; m < 8; ++m) cur[m] = *(const float4*)(odbase + (size_t)m * N);

  for (int g = 0; g < 8; ++g) {
    if (g < 7) {
#pragma unroll
      for (int m = 0; m < 8; ++m)
        nxt[m] = *(const float4*)(odbase + (size_t)((g + 1) * 8 + m) * N);
    }
    // per-row wave partial sums -> LDS
#pragma unroll
    for (int m = 0; m < 8; ++m) {
      float s = (cur[m].x + cur[m].y) + (cur[m].z + cur[m].w);
#pragma unroll
      for (int off = 32; off; off >>= 1) s += __shfl_down(s, off, 64);
      if (l == 0) wpart[w * 8 + m] = s;
    }
    __syncthreads();
    if (tid < 8) {  // one thread per row of the group
      const int r = g * 8 + tid;
      float rs = 0.f;
#pragma unroll
      for (int ww = 0; ww < 8; ++ww) rs += wpart[ww * 8 + tid];
      const float4 f = ldsfeat[r];
      const float pop = f.x;
      const float ratio = pop / (DELTA + rs);
      const float scale = ratio < 1.f ? ratio : 1.f;
      const float inv = 1.f / (DELTA + pop);
      const float odout = scale * rs;
      const float k1 = 1.f - odout * inv;  // stay = SIR*(1 - odout*inv)
      ((float4*)st0)[b * N + i0 + r] =
          make_float4(pop - odout, f.y * k1, f.z * k1, f.w * k1);
      wv[tid] = make_float4(scale, scale * f.y * inv, scale * f.z * inv,
                            scale * f.w * inv);
    }
    __syncthreads();
#pragma unroll
    for (int m = 0; m < 8; ++m) {
      const float4 wvm = wv[m];
      fma4(acc[0], cur[m].x, wvm);
      fma4(acc[1], cur[m].y, wvm);
      fma4(acc[2], cur[m].z, wvm);
      fma4(acc[3], cur[m].w, wvm);
    }
    if (g < 7) {
#pragma unroll
      for (int m = 0; m < 8; ++m) cur[m] = nxt[m];
    }
  }
  float4* pb = (float4*)part0 + (size_t)blockIdx.x * N + (w * 256 + l * 4);
#pragma unroll
  for (int c = 0; c < 4; ++c) pb[c] = acc[c];
}

// ---- prep1: pop1/inv1/SIR1 per (b,i) ----
__global__ void __launch_bounds__(256) prep1_kernel(const float* __restrict__ st0,
                                                    const float* __restrict__ part0,
                                                    float* __restrict__ pre1) {
  const int g = blockIdx.x * 256 + threadIdx.x;  // b*N + i
  const int b = g >> 11, i = g & (N - 1);
  float4 in = {0.f, 0.f, 0.f, 0.f};
  const float4* p = (const float4*)part0 + (size_t)b * NRB * N + i;
#pragma unroll 8
  for (int rb = 0; rb < NRB; ++rb) {
    const float4 v = p[(size_t)rb * N];
    in.x += v.x; in.y += v.y; in.z += v.z; in.w += v.w;
  }
  const float4 s0 = ((const float4*)st0)[g];
  const float pop = s0.x + in.x;  // pm0 + OD_in0
  const float inv = 1.f / (DELTA + pop);
  float4* o = (float4*)pre1 + (size_t)g * 2;
  o[0] = make_float4(pop, inv, s0.y, s0.z);
  o[1] = make_float4(s0.w, in.y, in.z, in.w);
}

// ---- fused1: t=1 rowsum + scale + column partials (NF=7+pad), OD1 read once ----
__global__ void __launch_bounds__(512) fused1_kernel(const float* __restrict__ OD,
                                                     const float* __restrict__ pre1,
                                                     float* __restrict__ part1,
                                                     float* __restrict__ st1) {
  const int tid = threadIdx.x, w = tid >> 6, l = tid & 63;
  const int b = blockIdx.x >> 5, rb = blockIdx.x & 31, i0 = rb * RPB;
  __shared__ float ldspre[RPB * 8];
  __shared__ float wpart[64];
  __shared__ float4 wva[8], wvb[8];
  if (tid < 128)
    ((float4*)ldspre)[tid] =
        ((const float4*)(pre1 + (size_t)(b * N + i0) * 8))[tid];
  __syncthreads();

  const float* odbase = OD + ((size_t)(b * 2 + 1) * N + i0) * N + w * 256 + l * 4;
  float4 accA[4] = {}, accB[4] = {};
  float4 cur[8], nxt[8];
#pragma unroll
  for (int m = 0; m < 8; ++m) cur[m] = *(const float4*)(odbase + (size_t)m * N);

  for (int g = 0; g < 8; ++g) {
    if (g < 7) {
#pragma unroll
      for (int m = 0; m < 8; ++m)
        nxt[m] = *(const float4*)(odbase + (size_t)((g + 1) * 8 + m) * N);
    }
#pragma unroll
    for (int m = 0; m < 8; ++m) {
      float s = (cur[m].x + cur[m].y) + (cur[m].z + cur[m].w);
#pragma unroll
      for (int off = 32; off; off >>= 1) s += __shfl_down(s, off, 64);
      if (l == 0) wpart[w * 8 + m] = s;
    }
    __syncthreads();
    if (tid < 8) {
      const int r = g * 8 + tid;
      float rs = 0.f;
#pragma unroll
      for (int ww = 0; ww < 8; ++ww) rs += wpart[ww * 8 + tid];
      const float* pr = &ldspre[r * 8];
      const float pop = pr[0], inv = pr[1];
      const float ratio = pop / (DELTA + rs);
      const float scale = ratio < 1.f ? ratio : 1.f;
      const float odout = scale * rs;
      const float k1 = 1.f - odout * inv;
      float4* s4 = (float4*)st1 + (size_t)(b * N + i0 + r) * 2;
      s4[0] = make_float4(pop - odout, pr[2] * k1, pr[3] * k1, pr[4] * k1);
      s4[1] = make_float4(pr[5] * k1, pr[6] * k1, pr[7] * k1, 0.f);
      const float si = scale * inv;
      wva[tid] = make_float4(scale, pr[2] * si, pr[3] * si, pr[4] * si);
      wvb[tid] = make_float4(pr[5] * si, pr[6] * si, pr[7] * si, 0.f);
    }
    __syncthreads();
#pragma unroll
    for (int m = 0; m < 8; ++m) {
      const float4 wa = wva[m], wb = wvb[m];
      fma4(accA[0], cur[m].x, wa);
      fma4(accB[0], cur[m].x, wb);
      fma4(accA[1], cur[m].y, wa);
      fma4(accB[1], cur[m].y, wb);
      fma4(accA[2], cur[m].z, wa);
      fma4(accB[2], cur[m].z, wb);
      fma4(accA[3], cur[m].w, wa);
      fma4(accB[3], cur[m].w, wb);
    }
    if (g < 7) {
#pragma unroll
      for (int m = 0; m < 8; ++m) cur[m] = nxt[m];
    }
  }
  float4* pb =
      (float4*)part1 + ((size_t)blockIdx.x * N + (w * 256 + l * 4)) * 2;
#pragma unroll
  for (int c = 0; c < 4; ++c) {
    pb[c * 2] = accA[c];
    pb[c * 2 + 1] = accB[c];
  }
}

// ---- reduce1: part1 -> acc1[b][j][8] ----
__global__ void __launch_bounds__(256) reduce1_kernel(const float* __restrict__ part1,
                                                      float* __restrict__ acc1) {
  const int g = blockIdx.x * 256 + threadIdx.x;  // b*N + j
  const int b = g >> 11, j = g & (N - 1);
  float4 a = {0.f, 0.f, 0.f, 0.f}, c = {0.f, 0.f, 0.f, 0.f};
  const float4* p = (const float4*)part1 + ((size_t)b * NRB * N + j) * 2;
#pragma unroll 8
  for (int rb = 0; rb < NRB; ++rb) {
    const float4 va = p[(size_t)rb * N * 2];
    const float4 vb = p[(size_t)rb * N * 2 + 1];
    a.x += va.x; a.y += va.y; a.z += va.z; a.w += va.w;
    c.x += vb.x; c.y += vb.y; c.z += vb.z; c.w += vb.w;
  }
  float4* o = (float4*)acc1 + (size_t)g * 2;
  o[0] = a;
  o[1] = c;
}

// ---- final: out = concat(pop2, relu(SIR2 @ K + bias)) ----
__global__ void __launch_bounds__(256) final_kernel(const float* __restrict__ st1,
                                                    const float* __restrict__ acc1,
                                                    const float* __restrict__ kern,
                                                    const float* __restrict__ bias,
                                                    float* __restrict__ out) {
  __shared__ float klds[12 * 64];
  const int tid = threadIdx.x;
  if (tid < 192) ((float4*)klds)[tid] = ((const float4*)kern)[tid];
  __syncthreads();
  const int p = blockIdx.x * 4 + (tid >> 6);  // b*N+n
  const int c = tid & 63;
  const float4* s4 = (const float4*)st1 + (size_t)p * 2;
  const float4 l0 = s4[0], l1 = s4[1];
  const float4* a4 = (const float4*)acc1 + (size_t)p * 2;
  const float4 a0 = a4[0], a1 = a4[1];
  const float S[12] = {l0.y, l0.z, l0.w, l1.x, l1.y, l1.z,
                       a0.y, a0.z, a0.w, a1.x, a1.y, a1.z};
  float sum = bias[c];
#pragma unroll
  for (int f = 0; f < 12; ++f) sum += S[f] * klds[f * 64 + c];
  float* o = out + (size_t)p * 65;
  o[1 + c] = sum > 0.f ? sum : 0.f;
  if (c == 0) o[0] = l0.x + a0.x;  // pop2 = pm1 + OD_in1
}

extern "C" void kernel_launch(void* const* d_in, const int* in_sizes, int n_in,
                              void* d_out, int out_size, void* d_ws, size_t ws_size,
                              hipStream_t stream) {
  const float* feat = (const float*)d_in[0];  // (8,2048,4)
  const float* OD   = (const float*)d_in[1];  // (8,2,2048,2048)
  const float* kern = (const float*)d_in[2];  // (12,64)
  const float* bias = (const float*)d_in[3];  // (64,)
  float* out = (float*)d_out;                 // (8,2048,65)
  float* ws = (float*)d_ws;

  float* st0   = ws + ST0_OFF;
  float* pre1  = ws + PRE_OFF;
  float* st1   = ws + ST1_OFF;
  float* part0 = ws + P0_OFF;
  float* part1 = ws + P1_OFF;
  float* acc1  = ws + ACC1_OFF;

  fused0_kernel<<<B * NRB, 512, 0, stream>>>(OD, feat, part0, st0);
  prep1_kernel<<<NB / 256, 256, 0, stream>>>(st0, part0, pre1);
  fused1_kernel<<<B * NRB, 512, 0, stream>>>(OD, pre1, part1, st1);
  reduce1_kernel<<<NB / 256, 256, 0, stream>>>(part1, acc1);
  final_kernel<<<NB / 4, 256, 0, stream>>>(st1, acc1, kern, bias, out);
}

// Round 5
// 398.307 us; speedup vs baseline: 1.0512x; 1.0085x over previous
//
#include <hip/hip_runtime.h>

// GraphSageConvOD: 2-iteration OD flow + SIR propagation + 12x64 dense + ReLU.
// B=8, T=2, N=2048. OD_all is 256 MB fp32; memory-bound.
//
// R5: 3 dispatches, each OD slice read exactly once at HBM BW.
//   fused0 : OD0 once -> part0[b][rb][j][4], st0[b][i][4]
//            (rowsum via shuffle+LDS, scale/w derived in-kernel, col partials)
//   fused1 : prologue reduces part0 cols for this block's 64 rows -> pop1/inv1/SIR1
//            in LDS; then OD1 once -> part1[b][rb][j][8], st1[b][i][8]
//   final2 : per point, 64 lanes butterfly-reduce part1 over rb, then
//            concat(pop2, relu(SIR2 @ K + bias))
//
// Kernel-side model: 21.3 + ~23 + ~3 us ~= 47 us (OD serial-dependency floor ~45).

#define DELTA 1e-7f
constexpr int B = 8, N = 2048;
constexpr int NB = B * N;     // 16384
constexpr int RPB = 64;       // rows per block (fused kernels)
constexpr int NRB = N / RPB;  // 32 row-blocks per batch

// ws float offsets
constexpr int ST0_OFF = 0;                     // [b][i][4] {pm0, stay0[3]}
constexpr int ST1_OFF = ST0_OFF + NB * 4;      // [b][i][8] {pm1, stay1[0..5], 0}
constexpr int P0_OFF  = ST1_OFF + NB * 8;      // part0 [b][rb][j][4]
constexpr int P1_OFF  = P0_OFF + B * NRB * N * 4;  // part1 [b][rb][j][2x float4]

__device__ __forceinline__ void fma4(float4& a, float s, const float4& w) {
  a.x = fmaf(s, w.x, a.x);
  a.y = fmaf(s, w.y, a.y);
  a.z = fmaf(s, w.z, a.z);
  a.w = fmaf(s, w.w, a.w);
}
__device__ __forceinline__ void add4(float4& a, const float4& v) {
  a.x += v.x; a.y += v.y; a.z += v.z; a.w += v.w;
}

// ---- fused0: t=0 rowsum + scale + column partials, OD0 read once ----
__global__ void __launch_bounds__(512) fused0_kernel(const float* __restrict__ OD,
                                                     const float* __restrict__ feat,
                                                     float* __restrict__ part0,
                                                     float* __restrict__ st0) {
  const int tid = threadIdx.x, w = tid >> 6, l = tid & 63;
  const int b = blockIdx.x >> 5, rb = blockIdx.x & 31, i0 = rb * RPB;
  __shared__ float4 ldsfeat[RPB];
  __shared__ float wpart[64];
  __shared__ float4 wv[8];
  if (tid < RPB) ldsfeat[tid] = ((const float4*)feat)[b * N + i0 + tid];
  __syncthreads();

  const float* odbase = OD + ((size_t)(b * 2) * N + i0) * N + w * 256 + l * 4;
  float4 acc[4] = {};
  float4 cur[8], nxt[8];
#pragma unroll
  for (int m = 0; m < 8; ++m) cur[m] = *(const float4*)(odbase + (size_t)m * N);

  for (int g = 0; g < 8; ++g) {
    if (g < 7) {
#pragma unroll
      for (int m = 0; m < 8; ++m)
        nxt[m] = *(const float4*)(odbase + (size_t)((g + 1) * 8 + m) * N);
    }
#pragma unroll
    for (int m = 0; m < 8; ++m) {
      float s = (cur[m].x + cur[m].y) + (cur[m].z + cur[m].w);
#pragma unroll
      for (int off = 32; off; off >>= 1) s += __shfl_down(s, off, 64);
      if (l == 0) wpart[w * 8 + m] = s;
    }
    __syncthreads();
    if (tid < 8) {  // one thread per row of the group
      const int r = g * 8 + tid;
      float rs = 0.f;
#pragma unroll
      for (int ww = 0; ww < 8; ++ww) rs += wpart[ww * 8 + tid];
      const float4 f = ldsfeat[r];
      const float pop = f.x;
      const float ratio = pop / (DELTA + rs);
      const float scale = ratio < 1.f ? ratio : 1.f;
      const float inv = 1.f / (DELTA + pop);
      const float odout = scale * rs;
      const float k1 = 1.f - odout * inv;
      ((float4*)st0)[b * N + i0 + r] =
          make_float4(pop - odout, f.y * k1, f.z * k1, f.w * k1);
      wv[tid] = make_float4(scale, scale * f.y * inv, scale * f.z * inv,
                            scale * f.w * inv);
    }
    __syncthreads();
#pragma unroll
    for (int m = 0; m < 8; ++m) {
      const float4 wvm = wv[m];
      fma4(acc[0], cur[m].x, wvm);
      fma4(acc[1], cur[m].y, wvm);
      fma4(acc[2], cur[m].z, wvm);
      fma4(acc[3], cur[m].w, wvm);
    }
    if (g < 7) {
#pragma unroll
      for (int m = 0; m < 8; ++m) cur[m] = nxt[m];
    }
  }
  float4* pb = (float4*)part0 + (size_t)blockIdx.x * N + (w * 256 + l * 4);
#pragma unroll
  for (int c = 0; c < 4; ++c) pb[c] = acc[c];
}

// ---- fused1: prologue (prep1 in LDS) + t=1 rowsum/scale/col-partials ----
__global__ void __launch_bounds__(512) fused1_kernel(const float* __restrict__ OD,
                                                     const float* __restrict__ st0,
                                                     const float* __restrict__ part0,
                                                     float* __restrict__ part1,
                                                     float* __restrict__ st1) {
  const int tid = threadIdx.x, w = tid >> 6, l = tid & 63;
  const int b = blockIdx.x >> 5, rb = blockIdx.x & 31, i0 = rb * RPB;
  __shared__ float ldspre[RPB * 8];
  __shared__ float4 redp[8][RPB];
  __shared__ float wpart[64];
  __shared__ float4 wva[8], wvb[8];

  // prologue: in[b][i][4] = sum_rbp part0[b][rbp][i][4] for this block's rows
  {
    const int row = tid & 63, rbg = tid >> 6;  // 8 groups of 4 rbp each
    const float4* p0 = (const float4*)part0 + (size_t)b * NRB * N + i0 + row;
    float4 s = {0.f, 0.f, 0.f, 0.f};
#pragma unroll
    for (int k = 0; k < 4; ++k) add4(s, p0[(size_t)(rbg * 4 + k) * N]);
    redp[rbg][row] = s;
  }
  __syncthreads();
  if (tid < RPB) {
    float4 in = redp[0][tid];
#pragma unroll
    for (int g = 1; g < 8; ++g) add4(in, redp[g][tid]);
    const float4 s0 = ((const float4*)st0)[b * N + i0 + tid];
    const float pop = s0.x + in.x;  // pm0 + OD_in0
    const float inv = 1.f / (DELTA + pop);
    float* o = &ldspre[tid * 8];
    o[0] = pop; o[1] = inv;
    o[2] = s0.y; o[3] = s0.z; o[4] = s0.w;
    o[5] = in.y; o[6] = in.z; o[7] = in.w;
  }
  __syncthreads();

  const float* odbase = OD + ((size_t)(b * 2 + 1) * N + i0) * N + w * 256 + l * 4;
  float4 accA[4] = {}, accB[4] = {};
  float4 cur[8], nxt[8];
#pragma unroll
  for (int m = 0; m < 8; ++m) cur[m] = *(const float4*)(odbase + (size_t)m * N);

  for (int g = 0; g < 8; ++g) {
    if (g < 7) {
#pragma unroll
      for (int m = 0; m < 8; ++m)
        nxt[m] = *(const float4*)(odbase + (size_t)((g + 1) * 8 + m) * N);
    }
#pragma unroll
    for (int m = 0; m < 8; ++m) {
      float s = (cur[m].x + cur[m].y) + (cur[m].z + cur[m].w);
#pragma unroll
      for (int off = 32; off; off >>= 1) s += __shfl_down(s, off, 64);
      if (l == 0) wpart[w * 8 + m] = s;
    }
    __syncthreads();
    if (tid < 8) {
      const int r = g * 8 + tid;
      float rs = 0.f;
#pragma unroll
      for (int ww = 0; ww < 8; ++ww) rs += wpart[ww * 8 + tid];
      const float* pr = &ldspre[r * 8];
      const float pop = pr[0], inv = pr[1];
      const float ratio = pop / (DELTA + rs);
      const float scale = ratio < 1.f ? ratio : 1.f;
      const float odout = scale * rs;
      const float k1 = 1.f - odout * inv;
      float4* s4 = (float4*)st1 + (size_t)(b * N + i0 + r) * 2;
      s4[0] = make_float4(pop - odout, pr[2] * k1, pr[3] * k1, pr[4] * k1);
      s4[1] = make_float4(pr[5] * k1, pr[6] * k1, pr[7] * k1, 0.f);
      const float si = scale * inv;
      wva[tid] = make_float4(scale, pr[2] * si, pr[3] * si, pr[4] * si);
      wvb[tid] = make_float4(pr[5] * si, pr[6] * si, pr[7] * si, 0.f);
    }
    __syncthreads();
#pragma unroll
    for (int m = 0; m < 8; ++m) {
      const float4 wa = wva[m], wb = wvb[m];
      fma4(accA[0], cur[m].x, wa);
      fma4(accB[0], cur[m].x, wb);
      fma4(accA[1], cur[m].y, wa);
      fma4(accB[1], cur[m].y, wb);
      fma4(accA[2], cur[m].z, wa);
      fma4(accB[2], cur[m].z, wb);
      fma4(accA[3], cur[m].w, wa);
      fma4(accB[3], cur[m].w, wb);
    }
    if (g < 7) {
#pragma unroll
      for (int m = 0; m < 8; ++m) cur[m] = nxt[m];
    }
  }
  float4* pb = (float4*)part1 + ((size_t)blockIdx.x * N + (w * 256 + l * 4)) * 2;
#pragma unroll
  for (int c = 0; c < 4; ++c) {
    pb[c * 2] = accA[c];
    pb[c * 2 + 1] = accB[c];
  }
}

// ---- final2: reduce part1 over rb + dense 12x64 + relu + concat pop2 ----
__global__ void __launch_bounds__(256) final2_kernel(const float* __restrict__ st1,
                                                     const float* __restrict__ part1,
                                                     const float* __restrict__ kern,
                                                     const float* __restrict__ bias,
                                                     float* __restrict__ out) {
  __shared__ float klds[12 * 64];
  __shared__ float s12[4][16];
  const int tid = threadIdx.x, quad = tid >> 6, c = tid & 63;
  if (tid < 192) ((float4*)klds)[tid] = ((const float4*)kern)[tid];

  const int p = blockIdx.x * 4 + quad;  // b*N + n
  const int b = p >> 11, n = p & (N - 1);
  // lane l: rb = l>>1, parity = l&1  (parity 0 -> accA, 1 -> accB)
  float4 v = ((const float4*)part1)[(((size_t)(b * NRB + (c >> 1)) * N + n) << 1) + (c & 1)];
#pragma unroll
  for (int off = 32; off >= 2; off >>= 1) {  // parity-preserving butterfly
    v.x += __shfl_down(v.x, off, 64);
    v.y += __shfl_down(v.y, off, 64);
    v.z += __shfl_down(v.z, off, 64);
    v.w += __shfl_down(v.w, off, 64);
  }
  if (c == 0) {  // v = accA total
    const float4 s0 = ((const float4*)st1)[(size_t)p * 2];
    const float4 s1 = ((const float4*)st1)[(size_t)p * 2 + 1];
    float* o = s12[quad];
    o[0] = s0.y; o[1] = s0.z; o[2] = s0.w;       // stay[0..2]
    o[3] = s1.x; o[4] = s1.y; o[5] = s1.z;       // stay[3..5]
    o[6] = v.y;  o[7] = v.z;  o[8] = v.w;        // in[0..2]
    o[12] = s0.x + v.x;                          // pop2 = pm1 + OD_in1
  }
  if (c == 1) {  // v = accB total
    float* o = s12[quad];
    o[9] = v.x; o[10] = v.y; o[11] = v.z;        // in[3..5]
  }
  __syncthreads();

  float sum = bias[c];
#pragma unroll
  for (int f = 0; f < 12; ++f) sum += s12[quad][f] * klds[f * 64 + c];
  float* o = out + (size_t)p * 65;
  o[1 + c] = sum > 0.f ? sum : 0.f;
  if (c == 0) o[0] = s12[quad][12];
}

extern "C" void kernel_launch(void* const* d_in, const int* in_sizes, int n_in,
                              void* d_out, int out_size, void* d_ws, size_t ws_size,
                              hipStream_t stream) {
  const float* feat = (const float*)d_in[0];  // (8,2048,4)
  const float* OD   = (const float*)d_in[1];  // (8,2,2048,2048)
  const float* kern = (const float*)d_in[2];  // (12,64)
  const float* bias = (const float*)d_in[3];  // (64,)
  float* out = (float*)d_out;                 // (8,2048,65)
  float* ws = (float*)d_ws;

  float* st0   = ws + ST0_OFF;
  float* st1   = ws + ST1_OFF;
  float* part0 = ws + P0_OFF;
  float* part1 = ws + P1_OFF;

  fused0_kernel<<<B * NRB, 512, 0, stream>>>(OD, feat, part0, st0);
  fused1_kernel<<<B * NRB, 512, 0, stream>>>(OD, st0, part0, part1, st1);
  final2_kernel<<<NB / 4, 256, 0, stream>>>(st1, part1, kern, bias, out);
}